// Round 7
// baseline (1188.629 us; speedup 1.0000x reference)
//
#include <hip/hip_runtime.h>
#include <stdint.h>

// Mamba-1.4B-like dims (fixed)
#define LSEQ 2048
#define HID  2048
#define IDIM 4096
#define NSTATE 16
#define RRANK 128
#define GDIM 160   // RRANK + 2*NSTATE

// chunked scan
#define GCHUNK 64
#define TCHUNK (LSEQ / GCHUNK)   // 32

typedef _Float16 f16x8 __attribute__((ext_vector_type(8)));
typedef _Float16 f16x2 __attribute__((ext_vector_type(2)));
typedef float f32x4 __attribute__((ext_vector_type(4)));

#define GLOAD_LDS16(g, l) __builtin_amdgcn_global_load_lds( \
    (const __attribute__((address_space(1))) void*)(g),     \
    (__attribute__((address_space(3))) void*)(l), 16, 0, 0)

__device__ __forceinline__ float softplus_f(float x) {
    if (x > 20.f) return x;
    return log1pf(__expf(x));
}
__device__ __forceinline__ float silu_f(float x) {
    return x / (1.f + __expf(-x));
}

// ---------------------------------------------------------------------------
// software grid barrier (all blocks must be co-resident — checked per kernel)
__device__ __forceinline__ void grid_barrier(int* cnt, int expected) {
    __syncthreads();
    if (threadIdx.x == 0) {
        __threadfence();               // device-scope release of prior writes
        atomicAdd(cnt, 1);
        while (__hip_atomic_load(cnt, __ATOMIC_ACQUIRE, __HIP_MEMORY_SCOPE_AGENT) < expected)
            __builtin_amdgcn_s_sleep(2);
    }
    __syncthreads();
}

// ---------------------------------------------------------------------------
// transpose one 64x64 tile of f32 (R x C) -> f16 (C x R)
__device__ __forceinline__ void transpose_tile(const float* __restrict__ in,
                                               _Float16* __restrict__ out,
                                               int R, int C, int tr, int tc,
                                               _Float16 (*tile)[66]) {
    const int c0 = tc * 64, r0 = tr * 64;
    const int t = threadIdx.x;
    const int tx = t & 15, ty = t >> 4;
    const int ox = t & 7, oy = t >> 3;
    const bool full = (c0 + 64 <= C) && (r0 + 64 <= R);
    if (full) {
        #pragma unroll
        for (int j = 0; j < 4; ++j) {
            int r = ty + j * 16;
            float4 v = *(const float4*)(in + (long)(r0 + r) * C + c0 + tx * 4);
            tile[r][tx * 4 + 0] = (_Float16)v.x;
            tile[r][tx * 4 + 1] = (_Float16)v.y;
            tile[r][tx * 4 + 2] = (_Float16)v.z;
            tile[r][tx * 4 + 3] = (_Float16)v.w;
        }
        __syncthreads();
        #pragma unroll
        for (int j = 0; j < 2; ++j) {
            int c = oy + j * 32;
            f16x8 v;
            #pragma unroll
            for (int e = 0; e < 8; ++e) v[e] = tile[ox * 8 + e][c];
            *(f16x8*)(out + (long)(c0 + c) * R + r0 + ox * 8) = v;
        }
    } else {
        #pragma unroll
        for (int j = 0; j < 4; ++j) {
            int r = ty + j * 16;
            #pragma unroll
            for (int e = 0; e < 4; ++e) {
                int c = c0 + tx * 4 + e;
                float v = (r0 + r < R && c < C) ? in[(long)(r0 + r) * C + c] : 0.f;
                tile[r][tx * 4 + e] = (_Float16)v;
            }
        }
        __syncthreads();
        #pragma unroll
        for (int j = 0; j < 2; ++j) {
            int c = c0 + oy + j * 32;
            if (c < C) {
                #pragma unroll
                for (int e = 0; e < 8; ++e) {
                    int r = r0 + ox * 8 + e;
                    if (r < R) out[(long)c * R + r] = tile[ox * 8 + e][oy + j * 32];
                }
            }
        }
    }
}

// ---------------------------------------------------------------------------
// prep: 4 weight transposes + X f32->f16 + barrier-counter zeroing
__global__ __launch_bounds__(256)
void prep_kernel(const float* __restrict__ x_in, const float* __restrict__ w_in,
                 const float* __restrict__ xw, const float* __restrict__ dtw,
                 const float* __restrict__ ow,
                 _Float16* __restrict__ Xf, _Float16* __restrict__ Wt1,
                 _Float16* __restrict__ Wt2, _Float16* __restrict__ Wt3,
                 _Float16* __restrict__ Wt4, int* __restrict__ ctr) {
    __shared__ _Float16 tile[64][66];
    int b = blockIdx.x;
    if (b == 0 && threadIdx.x < 8) ctr[threadIdx.x] = 0;
    if (b < 4096) { transpose_tile(w_in, Wt1, HID, 2 * IDIM, b / 128, b % 128, tile); return; }
    b -= 4096;
    if (b < 192) { transpose_tile(xw, Wt2, IDIM, GDIM, b / 3, b % 3, tile); return; }
    b -= 192;
    if (b < 128) { transpose_tile(dtw, Wt3, RRANK, IDIM, b / 64, b % 64, tile); return; }
    b -= 128;
    if (b < 2048) { transpose_tile(ow, Wt4, IDIM, HID, b / 32, b % 32, tile); return; }
    b -= 2048;
    long base = (long)b * 4096 + threadIdx.x * 16;
    #pragma unroll
    for (int h = 0; h < 2; ++h) {
        float4 a = *(const float4*)(x_in + base + h * 8);
        float4 c = *(const float4*)(x_in + base + h * 8 + 4);
        f16x8 v;
        v[0] = (_Float16)a.x; v[1] = (_Float16)a.y; v[2] = (_Float16)a.z; v[3] = (_Float16)a.w;
        v[4] = (_Float16)c.x; v[5] = (_Float16)c.y; v[6] = (_Float16)c.z; v[7] = (_Float16)c.w;
        *(f16x8*)(Xf + base + h * 8) = v;
    }
}

// ---------------------------------------------------------------------------
// GEMM core: C = A(M,K) @ Bt(N,K)^T, fp16 in, fp32 acc. BM=128, BN_=128.
// BK=64 via global_load_lds DMA + XOR chunk swizzle (slot q^(r&7)).
// K-split via blockIdx.z over [z*kc, z*kc+kc), output slab z.
#define BM 128
#define BK 64

template <typename CT, bool SOFTPLUS>
__device__ __forceinline__
void gemm_core(const _Float16* __restrict__ A, const _Float16* __restrict__ Bt,
               CT* __restrict__ C, int M, int N, int K, int kc,
               const float* __restrict__ bias,
               _Float16* __restrict__ As, _Float16* __restrict__ Bs) {
    const int m0 = blockIdx.y * BM;
    const int n0 = blockIdx.x * 128;
    const int t = threadIdx.x;
    const int wave = t >> 6;
    const int lane = t & 63;
    const int wm = wave >> 1, wn = wave & 1;
    const int lrow = lane & 15;
    const int quad = lane >> 4;
    const int sw8 = (lrow & 7) * 8;

    f32x4 acc[4][4];
    #pragma unroll
    for (int mi = 0; mi < 4; ++mi)
        #pragma unroll
        for (int ni = 0; ni < 4; ++ni)
            #pragma unroll
            for (int r = 0; r < 4; ++r)
                acc[mi][ni][r] = 0.f;

    const int k_begin = blockIdx.z * kc;
    const _Float16* pA[4];
    const _Float16* pB[4];
    #pragma unroll
    for (int j = 0; j < 4; ++j) {
        int s = j * 256 + t;
        int row = s >> 3;
        int ch = (s & 7) ^ (row & 7);
        pA[j] = A + (long)(m0 + row) * K + ch * 8 + k_begin;
        pB[j] = Bt + (long)(n0 + row) * K + ch * 8 + k_begin;
    }

    for (int kk = 0; kk < kc; kk += BK) {
        #pragma unroll
        for (int j = 0; j < 4; ++j) {
            GLOAD_LDS16(pA[j], As + (j * 256 + wave * 64) * 8);
            pA[j] += BK;
            GLOAD_LDS16(pB[j], Bs + (j * 256 + wave * 64) * 8);
            pB[j] += BK;
        }
        __syncthreads();

        #pragma unroll
        for (int h = 0; h < 2; ++h) {
            const int qoff = (h * 32 + quad * 8) ^ sw8;
            f16x8 af[4], bf[4];
            #pragma unroll
            for (int mi = 0; mi < 4; ++mi)
                af[mi] = *(const f16x8*)(As + (wm * 64 + mi * 16 + lrow) * BK + qoff);
            #pragma unroll
            for (int ni = 0; ni < 4; ++ni)
                bf[ni] = *(const f16x8*)(Bs + (wn * 64 + ni * 16 + lrow) * BK + qoff);
            #pragma unroll
            for (int mi = 0; mi < 4; ++mi)
                #pragma unroll
                for (int ni = 0; ni < 4; ++ni)
                    acc[mi][ni] = __builtin_amdgcn_mfma_f32_16x16x32_f16(af[mi], bf[ni], acc[mi][ni], 0, 0, 0);
        }
        __syncthreads();
    }

    CT* Cz = C + (long)blockIdx.z * M * N;
    #pragma unroll
    for (int mi = 0; mi < 4; ++mi) {
        #pragma unroll
        for (int ni = 0; ni < 4; ++ni) {
            int col = n0 + wn * 64 + ni * 16 + lrow;
            if (col < N) {
                float bv = SOFTPLUS ? bias[col] : 0.f;
                #pragma unroll
                for (int r = 0; r < 4; ++r) {
                    int row = m0 + wm * 64 + mi * 16 + quad * 4 + r;
                    float v = acc[mi][ni][r];
                    if (SOFTPLUS) v = softplus_f(v + bv);
                    Cz[(long)row * N + col] = (CT)v;
                }
            }
        }
    }
}

// ---------------------------------------------------------------------------
// in_proj GEMM + (grid barrier) + depthwise conv K=4 + SiLU.
// grid (64,16) = 1024 blocks; LDS 32KB -> 5/CU, launch_bounds(256,4) -> >=4/CU
// co-resident (capacity >= 1024). Barrier safe.
__global__ __launch_bounds__(256, 4)
void inproj_conv_kernel(const _Float16* __restrict__ Xf, const _Float16* __restrict__ Wt1,
                        _Float16* __restrict__ proj, const float* __restrict__ cw,
                        const float* __restrict__ cb, _Float16* __restrict__ u16,
                        int* __restrict__ ctr) {
    __shared__ _Float16 As[BM * BK];
    __shared__ _Float16 Bs[128 * BK];
    gemm_core<_Float16, false>(Xf, Wt1, proj, LSEQ, 2 * IDIM, HID, HID, nullptr, As, Bs);

    grid_barrier(ctr, 1024);

    // conv phase: 8 channels x 4 timesteps per thread
    int bid = blockIdx.y * gridDim.x + blockIdx.x;
    int idx = bid * 256 + threadIdx.x;          // (L/4)*(I/8) = 262144
    int i0 = (idx & 511) * 8;
    int t0 = (idx >> 9) * 4;
    f16x8 r[7];
    #pragma unroll
    for (int k = 0; k < 7; ++k) {
        int tt = t0 - 3 + k;
        if (tt >= 0) r[k] = *(const f16x8*)(proj + (long)tt * (2 * IDIM) + i0);
        else         r[k] = f16x8{0,0,0,0,0,0,0,0};
    }
    float4 wv[8]; float bb[8];
    #pragma unroll
    for (int j = 0; j < 8; ++j) { wv[j] = ((const float4*)cw)[i0 + j]; bb[j] = cb[i0 + j]; }
    #pragma unroll
    for (int tt = 0; tt < 4; ++tt) {
        f16x8 res;
        #pragma unroll
        for (int j = 0; j < 8; ++j) {
            float a = bb[j] + (float)r[tt][j] * wv[j].x + (float)r[tt+1][j] * wv[j].y
                            + (float)r[tt+2][j] * wv[j].z + (float)r[tt+3][j] * wv[j].w;
            res[j] = (_Float16)(a / (1.f + __expf(-a)));
        }
        *(f16x8*)(u16 + (long)(t0 + tt) * IDIM + i0) = res;
    }
}

// ---------------------------------------------------------------------------
// x_proj split-K x8 GEMM + (grid barrier) + reduce-to-ssm/dtin.
// grid (2,16,8) = 256 blocks -> 1/CU co-resident trivially.
__global__ __launch_bounds__(256)
void xproj_kernel(const _Float16* __restrict__ u16, const _Float16* __restrict__ Wt2,
                  float* __restrict__ xpart, float* __restrict__ ssm,
                  _Float16* __restrict__ dtin, int* __restrict__ ctr) {
    __shared__ _Float16 As[BM * BK];
    __shared__ _Float16 Bs[128 * BK];
    gemm_core<float, false>(u16, Wt2, xpart, LSEQ, 256, IDIM, IDIM / 8, nullptr, As, Bs);

    grid_barrier(ctr, 256);

    int bid = (blockIdx.z * gridDim.y + blockIdx.y) * gridDim.x + blockIdx.x;
    for (int k = bid * 256 + threadIdx.x; k < LSEQ * GDIM; k += 256 * 256) {
        int t = k / GDIM;
        int c = k - t * GDIM;
        float v = 0.f;
        #pragma unroll
        for (int z = 0; z < 8; ++z)
            v += xpart[((long)z * LSEQ + t) * 256 + c];
        ssm[k] = v;
        if (c < RRANK) dtin[t * RRANK + c] = (_Float16)v;
    }
}

// ---------------------------------------------------------------------------
// dt_proj: plain GEMM with fused bias+softplus epilogue
__global__ __launch_bounds__(256)
void dtproj_kernel(const _Float16* __restrict__ dtin, const _Float16* __restrict__ Wt3,
                   _Float16* __restrict__ dtf, const float* __restrict__ dtb) {
    __shared__ _Float16 As[BM * BK];
    __shared__ _Float16 Bs[128 * BK];
    gemm_core<_Float16, true>(dtin, Wt3, dtf, LSEQ, IDIM, RRANK, RRANK, dtb, As, Bs);
}

// ---------------------------------------------------------------------------
// out_proj split-K x2 GEMM (f16 partials) + (grid barrier) + reduce to f32 out.
// grid (16,16,2) = 512 blocks; LDS 32KB -> 5/CU, need 2/CU: co-resident.
__global__ __launch_bounds__(256, 2)
void outproj_kernel(const _Float16* __restrict__ y16, const _Float16* __restrict__ Wt4,
                    _Float16* __restrict__ opart, float* __restrict__ out,
                    int* __restrict__ ctr) {
    __shared__ _Float16 As[BM * BK];
    __shared__ _Float16 Bs[128 * BK];
    gemm_core<_Float16, false>(y16, Wt4, opart, LSEQ, HID, IDIM, IDIM / 2, nullptr, As, Bs);

    grid_barrier(ctr, 512);

    int bid = (blockIdx.z * gridDim.y + blockIdx.y) * gridDim.x + blockIdx.x;
    long base = ((long)bid * 256 + threadIdx.x) * 32;   // 131072 thr x 32 = L*H
    #pragma unroll
    for (int j = 0; j < 4; ++j) {
        f16x8 a = *(const f16x8*)(opart + base + j * 8);
        f16x8 b = *(const f16x8*)(opart + (long)LSEQ * HID + base + j * 8);
        float4 o0 = make_float4((float)a[0] + (float)b[0], (float)a[1] + (float)b[1],
                                (float)a[2] + (float)b[2], (float)a[3] + (float)b[3]);
        float4 o1 = make_float4((float)a[4] + (float)b[4], (float)a[5] + (float)b[5],
                                (float)a[6] + (float)b[6], (float)a[7] + (float)b[7]);
        *(float4*)(out + base + j * 8) = o0;
        *(float4*)(out + base + j * 8 + 4) = o1;
    }
}

// ---------------------------------------------------------------------------
// scan megakernel: pass1 -> barrier -> combine -> barrier -> pass3.
// grid 512 blocks, 2/CU co-resident (LDS 4KB, launch_bounds(256,2)).
__global__ __launch_bounds__(256, 2)
void scan_mega_kernel(const _Float16* __restrict__ dtf, const float* __restrict__ ssm,
                      const _Float16* __restrict__ u16, const _Float16* __restrict__ proj,
                      const float* __restrict__ A_log, const float* __restrict__ Dp,
                      _Float16* __restrict__ Pc, _Float16* __restrict__ Sc,
                      _Float16* __restrict__ y16, int* __restrict__ ctr1, int* __restrict__ ctr2) {
    __shared__ float Bsh[TCHUNK * 16];
    __shared__ float Csh[TCHUNK * 16];
    const int bx = blockIdx.x;
    const int c = bx >> 3;                  // chunk
    const int isl = bx & 7;                 // i-slab
    const int i0 = (isl * 256 + threadIdx.x) * 2;

    // stage B and C rows for this chunk (used in pass1 and pass3)
    for (int idx = threadIdx.x; idx < TCHUNK * 16; idx += 256) {
        int t = idx >> 4, n = idx & 15;
        Bsh[idx] = ssm[(c * TCHUNK + t) * GDIM + RRANK + n];
        Csh[idx] = ssm[(c * TCHUNK + t) * GDIM + RRANK + NSTATE + n];
    }
    __syncthreads();

    float A[2][16];
    #pragma unroll
    for (int ch = 0; ch < 2; ++ch) {
        const float4* Ap = (const float4*)(A_log + (long)(i0 + ch) * 16);
        #pragma unroll
        for (int q = 0; q < 4; ++q) {
            float4 v = Ap[q];
            A[ch][q * 4 + 0] = -__expf(v.x);
            A[ch][q * 4 + 1] = -__expf(v.y);
            A[ch][q * 4 + 2] = -__expf(v.z);
            A[ch][q * 4 + 3] = -__expf(v.w);
        }
    }

    // ---- pass 1: local end-state + P = exp(A * sum_dt)
    {
        float s[2][16];
        float sumdt[2] = {0.f, 0.f};
        #pragma unroll
        for (int ch = 0; ch < 2; ++ch)
            #pragma unroll
            for (int n = 0; n < 16; ++n) s[ch][n] = 0.f;

        long base = (long)c * TCHUNK * IDIM + i0;
        for (int t = 0; t < TCHUNK; ++t) {
            f16x2 dt2 = *(const f16x2*)(dtf + base + (long)t * IDIM);
            f16x2 u2  = *(const f16x2*)(u16 + base + (long)t * IDIM);
            #pragma unroll
            for (int ch = 0; ch < 2; ++ch) {
                float dt = (float)dt2[ch];
                float dtu = dt * (float)u2[ch];
                sumdt[ch] += dt;
                #pragma unroll
                for (int n = 0; n < 16; ++n) {
                    float dA = __expf(dt * A[ch][n]);
                    s[ch][n] = s[ch][n] * dA + dtu * Bsh[t * 16 + n];
                }
            }
        }
        long o = ((long)c * IDIM + i0) * 16;
        #pragma unroll
        for (int ch = 0; ch < 2; ++ch) {
            #pragma unroll
            for (int q = 0; q < 2; ++q) {
                f16x8 pv, sv;
                #pragma unroll
                for (int e = 0; e < 8; ++e) {
                    pv[e] = (_Float16)__expf(A[ch][q * 8 + e] * sumdt[ch]);
                    sv[e] = (_Float16)s[ch][q * 8 + e];
                }
                *(f16x8*)(Pc + o + ch * 16 + q * 8) = pv;
                *(f16x8*)(Sc + o + ch * 16 + q * 8) = sv;
            }
        }
    }

    grid_barrier(ctr1, 512);

    // ---- combine: sequential over chunks per (i,n) pair; Init overwrites Sc
    {
        int pair = bx * 256 + threadIdx.x;
        if (pair < IDIM * 16 / 2) {
            const long stride = (long)IDIM * 16;
            const long off = (long)pair * 2;
            f16x2 p4[4], s4[4];
            #pragma unroll
            for (int k = 0; k < 4; ++k) {
                p4[k] = *(const f16x2*)(Pc + (long)k * stride + off);
                s4[k] = *(const f16x2*)(Sc + (long)k * stride + off);
            }
            float c0 = 0.f, c1 = 0.f;
            for (int g = 0; g < GCHUNK / 4; ++g) {
                f16x2 pc[4], sc[4];
                #pragma unroll
                for (int k = 0; k < 4; ++k) { pc[k] = p4[k]; sc[k] = s4[k]; }
                if (g + 1 < GCHUNK / 4) {
                    #pragma unroll
                    for (int k = 0; k < 4; ++k) {
                        long o2 = (long)((g + 1) * 4 + k) * stride + off;
                        p4[k] = *(const f16x2*)(Pc + o2);
                        s4[k] = *(const f16x2*)(Sc + o2);
                    }
                }
                #pragma unroll
                for (int k = 0; k < 4; ++k) {
                    long o = (long)(g * 4 + k) * stride + off;
                    *(f16x2*)(Sc + o) = f16x2{(_Float16)c0, (_Float16)c1};
                    c0 = c0 * (float)pc[k][0] + (float)sc[k][0];
                    c1 = c1 * (float)pc[k][1] + (float)sc[k][1];
                }
            }
        }
    }

    grid_barrier(ctr2, 512);

    // ---- pass 3: rerun chunk from true init, emit gated output
    {
        float2 Dv = *(const float2*)(Dp + i0);
        float s[2][16];
        long o = ((long)c * IDIM + i0) * 16;
        #pragma unroll
        for (int ch = 0; ch < 2; ++ch)
            #pragma unroll
            for (int q = 0; q < 2; ++q) {
                f16x8 v = *(const f16x8*)(Sc + o + ch * 16 + q * 8);
                #pragma unroll
                for (int e = 0; e < 8; ++e) s[ch][q * 8 + e] = (float)v[e];
            }

        long base = (long)c * TCHUNK * IDIM + i0;
        for (int t = 0; t < TCHUNK; ++t) {
            f16x2 dt2 = *(const f16x2*)(dtf + base + (long)t * IDIM);
            f16x2 u2  = *(const f16x2*)(u16 + base + (long)t * IDIM);
            int tg = c * TCHUNK + t;
            f16x2 g2 = *(const f16x2*)(proj + (long)tg * (2 * IDIM) + IDIM + i0);
            f16x2 res;
            #pragma unroll
            for (int ch = 0; ch < 2; ++ch) {
                float dt = (float)dt2[ch];
                float uv = (float)u2[ch];
                float dtu = dt * uv;
                float y = 0.f;
                #pragma unroll
                for (int n = 0; n < 16; ++n) {
                    float dA = __expf(dt * A[ch][n]);
                    s[ch][n] = s[ch][n] * dA + dtu * Bsh[t * 16 + n];
                    y += s[ch][n] * Csh[t * 16 + n];
                }
                float g = (float)g2[ch];
                float Dch = ch ? Dv.y : Dv.x;
                res[ch] = (_Float16)((y + uv * Dch) * silu_f(g));
            }
            *(f16x2*)(y16 + base + (long)t * IDIM) = res;
        }
    }
}

// ---------------------------------------------------------------------------
extern "C" void kernel_launch(void* const* d_in, const int* in_sizes, int n_in,
                              void* d_out, int out_size, void* d_ws, size_t ws_size,
                              hipStream_t stream) {
    const float* x_in  = (const float*)d_in[0];
    const float* w_in  = (const float*)d_in[1];
    const float* cw    = (const float*)d_in[2];
    const float* cb    = (const float*)d_in[3];
    const float* xw    = (const float*)d_in[4];
    const float* dtw   = (const float*)d_in[5];
    const float* dtb   = (const float*)d_in[6];
    const float* alog  = (const float*)d_in[7];
    const float* Dp    = (const float*)d_in[8];
    const float* ow    = (const float*)d_in[9];
    float* out = (float*)d_out;

    char* p = (char*)d_ws;
    auto alloc = [&](size_t bytes) { char* r = p; p += (bytes + 255) & ~255ull; return r; };
    _Float16* Xf    = (_Float16*)alloc((size_t)LSEQ * HID * 2);
    _Float16* Wt1   = (_Float16*)alloc((size_t)2 * IDIM * HID * 2);      // (2I,H); dead after in_proj
    _Float16* proj  = (_Float16*)alloc((size_t)LSEQ * 2 * IDIM * 2);
    _Float16* u16   = (_Float16*)alloc((size_t)LSEQ * IDIM * 2);
    _Float16* Wt2   = (_Float16*)alloc((size_t)256 * IDIM * 2);          // (GDIM pad 256, I)
    float*    ssm   = (float*)alloc((size_t)LSEQ * GDIM * 4);
    _Float16* dtin  = (_Float16*)alloc((size_t)LSEQ * RRANK * 2);
    _Float16* Wt3   = (_Float16*)alloc((size_t)IDIM * RRANK * 2);        // (I,R)
    _Float16* dtf   = (_Float16*)alloc((size_t)LSEQ * IDIM * 2);
    _Float16* Wt4   = (_Float16*)alloc((size_t)HID * IDIM * 2);          // (H,I)
    _Float16* y16   = (_Float16*)alloc((size_t)LSEQ * IDIM * 2);
    int*      ctr   = (int*)alloc(256);                                  // barrier counters

    // aliases into dead Wt1 region (33.5 MB), lifetime-ordered:
    //   xpart (xproj) -> Pc/Sc f16 (scan) -> opart f16 (out_proj)
    float* xpart = (float*)Wt1;                        // 8 x 2048 x 256 f32 = 16.8 MB
    _Float16* Pc = (_Float16*)Wt1;                     // G*I*16 f16 = 8.4 MB
    _Float16* Sc = Pc + (size_t)GCHUNK * IDIM * 16;    // 8.4 MB
    _Float16* opart = (_Float16*)Wt1;                  // 2 x L*H f16 = 16.8 MB

    // 1. prep (+ zero barrier counters)
    prep_kernel<<<7488, 256, 0, stream>>>(x_in, w_in, xw, dtw, ow, Xf, Wt1, Wt2, Wt3, Wt4, ctr);
    // 2. in_proj GEMM + conv + SiLU (fused)
    inproj_conv_kernel<<<dim3(2 * IDIM / 128, LSEQ / BM), 256, 0, stream>>>(
        Xf, Wt1, proj, cw, cb, u16, ctr + 0);
    // 3. x_proj split-K x8 + reduce (fused)
    xproj_kernel<<<dim3(2, LSEQ / BM, 8), 256, 0, stream>>>(
        u16, Wt2, xpart, ssm, dtin, ctr + 1);
    // 4. dt_proj (+bias+softplus)
    dtproj_kernel<<<dim3(IDIM / 128, LSEQ / BM), 256, 0, stream>>>(dtin, Wt3, dtf, dtb);
    // 5. scan megakernel (pass1 + combine + pass3)
    scan_mega_kernel<<<512, 256, 0, stream>>>(
        dtf, ssm, u16, proj, alog, Dp, Pc, Sc, y16, ctr + 2, ctr + 3);
    // 6. out_proj split-K x2 + reduce (fused)
    outproj_kernel<<<dim3(HID / 128, LSEQ / BM, 2), 256, 0, stream>>>(
        y16, Wt4, opart, out, ctr + 4);
}

// Round 8
// 463.203 us; speedup vs baseline: 2.5661x; 2.5661x over previous
//
#include <hip/hip_runtime.h>
#include <stdint.h>

// Mamba-1.4B-like dims (fixed)
#define LSEQ 2048
#define HID  2048
#define IDIM 4096
#define NSTATE 16
#define RRANK 128
#define GDIM 160   // RRANK + 2*NSTATE

// chunked scan
#define GCHUNK 64
#define TCHUNK (LSEQ / GCHUNK)   // 32

typedef _Float16 f16x8 __attribute__((ext_vector_type(8)));
typedef _Float16 f16x2 __attribute__((ext_vector_type(2)));
typedef float f32x4 __attribute__((ext_vector_type(4)));

#define GLOAD_LDS16(g, l) __builtin_amdgcn_global_load_lds( \
    (const __attribute__((address_space(1))) void*)(g),     \
    (__attribute__((address_space(3))) void*)(l), 16, 0, 0)

__device__ __forceinline__ float softplus_f(float x) {
    if (x > 20.f) return x;
    return log1pf(__expf(x));
}
__device__ __forceinline__ float silu_f(float x) {
    return x / (1.f + __expf(-x));
}

// ---------------------------------------------------------------------------
// transpose one 64x64 tile of f32 (R x C) -> f16 (C x R)
__device__ __forceinline__ void transpose_tile(const float* __restrict__ in,
                                               _Float16* __restrict__ out,
                                               int R, int C, int tr, int tc,
                                               _Float16 (*tile)[66]) {
    const int c0 = tc * 64, r0 = tr * 64;
    const int t = threadIdx.x;
    const int tx = t & 15, ty = t >> 4;
    const int ox = t & 7, oy = t >> 3;
    const bool full = (c0 + 64 <= C) && (r0 + 64 <= R);
    if (full) {
        #pragma unroll
        for (int j = 0; j < 4; ++j) {
            int r = ty + j * 16;
            float4 v = *(const float4*)(in + (long)(r0 + r) * C + c0 + tx * 4);
            tile[r][tx * 4 + 0] = (_Float16)v.x;
            tile[r][tx * 4 + 1] = (_Float16)v.y;
            tile[r][tx * 4 + 2] = (_Float16)v.z;
            tile[r][tx * 4 + 3] = (_Float16)v.w;
        }
        __syncthreads();
        #pragma unroll
        for (int j = 0; j < 2; ++j) {
            int c = oy + j * 32;
            f16x8 v;
            #pragma unroll
            for (int e = 0; e < 8; ++e) v[e] = tile[ox * 8 + e][c];
            *(f16x8*)(out + (long)(c0 + c) * R + r0 + ox * 8) = v;
        }
    } else {
        #pragma unroll
        for (int j = 0; j < 4; ++j) {
            int r = ty + j * 16;
            #pragma unroll
            for (int e = 0; e < 4; ++e) {
                int c = c0 + tx * 4 + e;
                float v = (r0 + r < R && c < C) ? in[(long)(r0 + r) * C + c] : 0.f;
                tile[r][tx * 4 + e] = (_Float16)v;
            }
        }
        __syncthreads();
        #pragma unroll
        for (int j = 0; j < 2; ++j) {
            int c = c0 + oy + j * 32;
            if (c < C) {
                #pragma unroll
                for (int e = 0; e < 8; ++e) {
                    int r = r0 + ox * 8 + e;
                    if (r < R) out[(long)c * R + r] = tile[ox * 8 + e][oy + j * 32];
                }
            }
        }
    }
}

// ---------------------------------------------------------------------------
// prep: Wt1 transpose (needed first) + X f32->f16.  4096 + 1024 = 5120 blocks
__global__ __launch_bounds__(256)
void prep_kernel(const float* __restrict__ x_in, const float* __restrict__ w_in,
                 _Float16* __restrict__ Xf, _Float16* __restrict__ Wt1) {
    __shared__ _Float16 tile[64][66];
    int b = blockIdx.x;
    if (b < 4096) { transpose_tile(w_in, Wt1, HID, 2 * IDIM, b / 128, b % 128, tile); return; }
    b -= 4096;
    long base = (long)b * 4096 + threadIdx.x * 16;
    #pragma unroll
    for (int h = 0; h < 2; ++h) {
        float4 a = *(const float4*)(x_in + base + h * 8);
        float4 c = *(const float4*)(x_in + base + h * 8 + 4);
        f16x8 v;
        v[0] = (_Float16)a.x; v[1] = (_Float16)a.y; v[2] = (_Float16)a.z; v[3] = (_Float16)a.w;
        v[4] = (_Float16)c.x; v[5] = (_Float16)c.y; v[6] = (_Float16)c.z; v[7] = (_Float16)c.w;
        *(f16x8*)(Xf + base + h * 8) = v;
    }
}

// ---------------------------------------------------------------------------
// GEMM core: C = A(M,K) @ Bt(N,K)^T, fp16 in, fp32 acc. BM=128, BN=128.
// BK=64 via global_load_lds DMA + XOR chunk swizzle (slot q^(r&7)).
#define BM 128
#define BK 64

template <typename CT, bool SOFTPLUS>
__device__ __forceinline__
void gemm_core(const _Float16* __restrict__ A, const _Float16* __restrict__ Bt,
               CT* __restrict__ C, int M, int N, int K, int kc,
               const float* __restrict__ bias,
               _Float16* __restrict__ As, _Float16* __restrict__ Bs,
               int m0, int n0, int zz) {
    const int t = threadIdx.x;
    const int wave = t >> 6;
    const int lane = t & 63;
    const int wm = wave >> 1, wn = wave & 1;
    const int lrow = lane & 15;
    const int quad = lane >> 4;
    const int sw8 = (lrow & 7) * 8;

    f32x4 acc[4][4];
    #pragma unroll
    for (int mi = 0; mi < 4; ++mi)
        #pragma unroll
        for (int ni = 0; ni < 4; ++ni)
            #pragma unroll
            for (int r = 0; r < 4; ++r)
                acc[mi][ni][r] = 0.f;

    const int k_begin = zz * kc;
    const _Float16* pA[4];
    const _Float16* pB[4];
    #pragma unroll
    for (int j = 0; j < 4; ++j) {
        int s = j * 256 + t;
        int row = s >> 3;
        int ch = (s & 7) ^ (row & 7);
        pA[j] = A + (long)(m0 + row) * K + ch * 8 + k_begin;
        pB[j] = Bt + (long)(n0 + row) * K + ch * 8 + k_begin;
    }

    for (int kk = 0; kk < kc; kk += BK) {
        #pragma unroll
        for (int j = 0; j < 4; ++j) {
            GLOAD_LDS16(pA[j], As + (j * 256 + wave * 64) * 8);
            pA[j] += BK;
            GLOAD_LDS16(pB[j], Bs + (j * 256 + wave * 64) * 8);
            pB[j] += BK;
        }
        __syncthreads();

        #pragma unroll
        for (int h = 0; h < 2; ++h) {
            const int qoff = (h * 32 + quad * 8) ^ sw8;
            f16x8 af[4], bf[4];
            #pragma unroll
            for (int mi = 0; mi < 4; ++mi)
                af[mi] = *(const f16x8*)(As + (wm * 64 + mi * 16 + lrow) * BK + qoff);
            #pragma unroll
            for (int ni = 0; ni < 4; ++ni)
                bf[ni] = *(const f16x8*)(Bs + (wn * 64 + ni * 16 + lrow) * BK + qoff);
            #pragma unroll
            for (int mi = 0; mi < 4; ++mi)
                #pragma unroll
                for (int ni = 0; ni < 4; ++ni)
                    acc[mi][ni] = __builtin_amdgcn_mfma_f32_16x16x32_f16(af[mi], bf[ni], acc[mi][ni], 0, 0, 0);
        }
        __syncthreads();
    }

    CT* Cz = C + (long)zz * M * N;
    #pragma unroll
    for (int mi = 0; mi < 4; ++mi) {
        #pragma unroll
        for (int ni = 0; ni < 4; ++ni) {
            int col = n0 + wn * 64 + ni * 16 + lrow;
            if (col < N) {
                float bv = SOFTPLUS ? bias[col] : 0.f;
                #pragma unroll
                for (int r = 0; r < 4; ++r) {
                    int row = m0 + wm * 64 + mi * 16 + quad * 4 + r;
                    float v = acc[mi][ni][r];
                    if (SOFTPLUS) v = softplus_f(v + bv);
                    Cz[(long)row * N + col] = (CT)v;
                }
            }
        }
    }
}

// standalone GEMM wrapper (xproj / dtproj / outproj)
template <typename CT, bool SOFTPLUS>
__global__ __launch_bounds__(256)
void gemm_bt_kernel(const _Float16* __restrict__ A, const _Float16* __restrict__ Bt,
                    CT* __restrict__ C, int M, int N, int K, int kc,
                    const float* __restrict__ bias) {
    __shared__ _Float16 As[BM * BK];
    __shared__ _Float16 Bs[128 * BK];
    gemm_core<CT, SOFTPLUS>(A, Bt, C, M, N, K, kc, bias, As, Bs,
                            blockIdx.y * BM, blockIdx.x * 128, blockIdx.z);
}

// ---------------------------------------------------------------------------
// in_proj GEMM (1024 blocks) + independent Wt2/Wt3/Wt4 transposes (2368 blocks)
// in one dispatch — NO barrier; transposes feed later kernels (stream order).
__global__ __launch_bounds__(256)
void inproj_plus_kernel(const _Float16* __restrict__ Xf, const _Float16* __restrict__ Wt1,
                        _Float16* __restrict__ proj,
                        const float* __restrict__ xw, const float* __restrict__ dtw,
                        const float* __restrict__ ow,
                        _Float16* __restrict__ Wt2, _Float16* __restrict__ Wt3,
                        _Float16* __restrict__ Wt4) {
    __shared__ _Float16 smem[BM * BK + 128 * BK];   // 32 KB
    int b = blockIdx.x;
    if (b < 1024) {
        gemm_core<_Float16, false>(Xf, Wt1, proj, LSEQ, 2 * IDIM, HID, HID, nullptr,
                                   smem, smem + BM * BK, (b >> 6) * BM, (b & 63) * 128, 0);
        return;
    }
    b -= 1024;
    _Float16 (*tile)[66] = (_Float16 (*)[66])smem;
    if (b < 192) { transpose_tile(xw, Wt2, IDIM, GDIM, b / 3, b % 3, tile); return; }
    b -= 192;
    if (b < 128) { transpose_tile(dtw, Wt3, RRANK, IDIM, b / 64, b % 64, tile); return; }
    b -= 128;
    transpose_tile(ow, Wt4, IDIM, HID, b / 32, b % 32, tile);
}

// ---------------------------------------------------------------------------
// x_proj split-K reduce: sum 16 partial slabs (L,256), write ssm (L,160) f32
// and dt_in (L,128) f16.
__global__ void xproj_reduce_kernel(const float* __restrict__ part, float* __restrict__ ssm,
                                    _Float16* __restrict__ dtin) {
    int idx = blockIdx.x * 256 + threadIdx.x;
    if (idx >= LSEQ * GDIM) return;
    int t = idx / GDIM;
    int c = idx - t * GDIM;
    float v = 0.f;
    #pragma unroll
    for (int k = 0; k < 16; ++k)
        v += part[((long)k * LSEQ + t) * 256 + c];
    ssm[idx] = v;
    if (c < RRANK) dtin[t * RRANK + c] = (_Float16)v;
}

// ---------------------------------------------------------------------------
// out_proj split-K reduce (f16 partials): out = part0 + part1 -> f32
__global__ void opart_reduce_kernel(const _Float16* __restrict__ part, float* __restrict__ out) {
    long base = ((long)blockIdx.x * 256 + threadIdx.x) * 32;
    #pragma unroll
    for (int j = 0; j < 4; ++j) {
        f16x8 a = *(const f16x8*)(part + base + j * 8);
        f16x8 b = *(const f16x8*)(part + (long)LSEQ * HID + base + j * 8);
        float4 o0 = make_float4((float)a[0] + (float)b[0], (float)a[1] + (float)b[1],
                                (float)a[2] + (float)b[2], (float)a[3] + (float)b[3]);
        float4 o1 = make_float4((float)a[4] + (float)b[4], (float)a[5] + (float)b[5],
                                (float)a[6] + (float)b[6], (float)a[7] + (float)b[7]);
        *(float4*)(out + base + j * 8) = o0;
        *(float4*)(out + base + j * 8 + 4) = o1;
    }
}

// ---------------------------------------------------------------------------
// depthwise causal conv (K=4) + bias + SiLU; 8 channels x 4 timesteps/thread
__global__ void conv_silu_kernel(const _Float16* __restrict__ proj, const float* __restrict__ w,
                                 const float* __restrict__ b, _Float16* __restrict__ u16) {
    int idx = blockIdx.x * 256 + threadIdx.x;   // (L/4) * (I/8)
    int i0 = (idx & 511) * 8;
    int t0 = (idx >> 9) * 4;
    f16x8 r[7];
    #pragma unroll
    for (int k = 0; k < 7; ++k) {
        int tt = t0 - 3 + k;
        if (tt >= 0) r[k] = *(const f16x8*)(proj + (long)tt * (2 * IDIM) + i0);
        else         r[k] = f16x8{0,0,0,0,0,0,0,0};
    }
    float4 wv[8]; float bb[8];
    #pragma unroll
    for (int j = 0; j < 8; ++j) { wv[j] = ((const float4*)w)[i0 + j]; bb[j] = b[i0 + j]; }
    #pragma unroll
    for (int tt = 0; tt < 4; ++tt) {
        f16x8 res;
        #pragma unroll
        for (int j = 0; j < 8; ++j) {
            float a = bb[j] + (float)r[tt][j] * wv[j].x + (float)r[tt+1][j] * wv[j].y
                            + (float)r[tt+2][j] * wv[j].z + (float)r[tt+3][j] * wv[j].w;
            res[j] = (_Float16)(a / (1.f + __expf(-a)));
        }
        *(f16x8*)(u16 + (long)(t0 + tt) * IDIM + i0) = res;
    }
}

// ---------------------------------------------------------------------------
// Chunked selective scan, 2 channels/thread, f16 chunk states.
__global__ __launch_bounds__(256)
void scan_pass1_kernel(const _Float16* __restrict__ dtf, const float* __restrict__ ssm,
                       const _Float16* __restrict__ u16, const float* __restrict__ A_log,
                       _Float16* __restrict__ Pc, _Float16* __restrict__ Sc) {
    const int c = blockIdx.y;
    const int i0 = (blockIdx.x * 256 + threadIdx.x) * 2;

    __shared__ float Bs[TCHUNK * 16];
    for (int idx = threadIdx.x; idx < TCHUNK * 16; idx += 256) {
        int t = idx >> 4, n = idx & 15;
        Bs[idx] = ssm[(c * TCHUNK + t) * GDIM + RRANK + n];
    }
    __syncthreads();

    float A[2][16];
    #pragma unroll
    for (int ch = 0; ch < 2; ++ch) {
        const float4* Ap = (const float4*)(A_log + (long)(i0 + ch) * 16);
        #pragma unroll
        for (int q = 0; q < 4; ++q) {
            float4 v = Ap[q];
            A[ch][q * 4 + 0] = -__expf(v.x);
            A[ch][q * 4 + 1] = -__expf(v.y);
            A[ch][q * 4 + 2] = -__expf(v.z);
            A[ch][q * 4 + 3] = -__expf(v.w);
        }
    }

    float s[2][16];
    float sumdt[2] = {0.f, 0.f};
    #pragma unroll
    for (int ch = 0; ch < 2; ++ch)
        #pragma unroll
        for (int n = 0; n < 16; ++n) s[ch][n] = 0.f;

    long base = (long)c * TCHUNK * IDIM + i0;
    for (int t = 0; t < TCHUNK; ++t) {
        f16x2 dt2 = *(const f16x2*)(dtf + base + (long)t * IDIM);
        f16x2 u2  = *(const f16x2*)(u16 + base + (long)t * IDIM);
        #pragma unroll
        for (int ch = 0; ch < 2; ++ch) {
            float dt = (float)dt2[ch];
            float dtu = dt * (float)u2[ch];
            sumdt[ch] += dt;
            #pragma unroll
            for (int n = 0; n < 16; ++n) {
                float dA = __expf(dt * A[ch][n]);
                s[ch][n] = s[ch][n] * dA + dtu * Bs[t * 16 + n];
            }
        }
    }

    long o = ((long)c * IDIM + i0) * 16;
    #pragma unroll
    for (int ch = 0; ch < 2; ++ch) {
        #pragma unroll
        for (int q = 0; q < 2; ++q) {
            f16x8 pv, sv;
            #pragma unroll
            for (int e = 0; e < 8; ++e) {
                pv[e] = (_Float16)__expf(A[ch][q * 8 + e] * sumdt[ch]);
                sv[e] = (_Float16)s[ch][q * 8 + e];
            }
            *(f16x8*)(Pc + o + ch * 16 + q * 8) = pv;
            *(f16x8*)(Sc + o + ch * 16 + q * 8) = sv;
        }
    }
}

// Combine: sequential over G chunks per (i,n) pair, f32 carry, group-of-4 prefetch.
__global__ void scan_combine_kernel(const _Float16* __restrict__ Pc, _Float16* __restrict__ ScInit) {
    int tid = blockIdx.x * 256 + threadIdx.x;   // I*16/2 pairs
    const long stride = (long)IDIM * 16;
    const long off = (long)tid * 2;
    f16x2 p4[4], s4[4];
    #pragma unroll
    for (int k = 0; k < 4; ++k) {
        p4[k] = *(const f16x2*)(Pc + (long)k * stride + off);
        s4[k] = *(const f16x2*)(ScInit + (long)k * stride + off);
    }
    float c0 = 0.f, c1 = 0.f;
    for (int g = 0; g < GCHUNK / 4; ++g) {
        f16x2 pc[4], sc[4];
        #pragma unroll
        for (int k = 0; k < 4; ++k) { pc[k] = p4[k]; sc[k] = s4[k]; }
        if (g + 1 < GCHUNK / 4) {
            #pragma unroll
            for (int k = 0; k < 4; ++k) {
                long o2 = (long)((g + 1) * 4 + k) * stride + off;
                p4[k] = *(const f16x2*)(Pc + o2);
                s4[k] = *(const f16x2*)(ScInit + o2);
            }
        }
        #pragma unroll
        for (int k = 0; k < 4; ++k) {
            long o = (long)(g * 4 + k) * stride + off;
            *(f16x2*)(ScInit + o) = f16x2{(_Float16)c0, (_Float16)c1};
            c0 = c0 * (float)pc[k][0] + (float)sc[k][0];
            c1 = c1 * (float)pc[k][1] + (float)sc[k][1];
        }
    }
}

__global__ __launch_bounds__(256)
void scan_pass3_kernel(const _Float16* __restrict__ dtf, const float* __restrict__ ssm,
                       const _Float16* __restrict__ u16, const _Float16* __restrict__ proj,
                       const float* __restrict__ A_log, const float* __restrict__ Dp,
                       const _Float16* __restrict__ Init, _Float16* __restrict__ y16) {
    const int c = blockIdx.y;
    const int i0 = (blockIdx.x * 256 + threadIdx.x) * 2;

    __shared__ float Bs[TCHUNK * 16];
    __shared__ float Cs[TCHUNK * 16];
    for (int idx = threadIdx.x; idx < TCHUNK * 16; idx += 256) {
        int t = idx >> 4, n = idx & 15;
        Bs[idx] = ssm[(c * TCHUNK + t) * GDIM + RRANK + n];
        Cs[idx] = ssm[(c * TCHUNK + t) * GDIM + RRANK + NSTATE + n];
    }
    __syncthreads();

    float A[2][16];
    #pragma unroll
    for (int ch = 0; ch < 2; ++ch) {
        const float4* Ap = (const float4*)(A_log + (long)(i0 + ch) * 16);
        #pragma unroll
        for (int q = 0; q < 4; ++q) {
            float4 v = Ap[q];
            A[ch][q * 4 + 0] = -__expf(v.x);
            A[ch][q * 4 + 1] = -__expf(v.y);
            A[ch][q * 4 + 2] = -__expf(v.z);
            A[ch][q * 4 + 3] = -__expf(v.w);
        }
    }
    float2 Dv = *(const float2*)(Dp + i0);

    float s[2][16];
    {
        long o = ((long)c * IDIM + i0) * 16;
        #pragma unroll
        for (int ch = 0; ch < 2; ++ch)
            #pragma unroll
            for (int q = 0; q < 2; ++q) {
                f16x8 v = *(const f16x8*)(Init + o + ch * 16 + q * 8);
                #pragma unroll
                for (int e = 0; e < 8; ++e) s[ch][q * 8 + e] = (float)v[e];
            }
    }

    long base = (long)c * TCHUNK * IDIM + i0;
    for (int t = 0; t < TCHUNK; ++t) {
        f16x2 dt2 = *(const f16x2*)(dtf + base + (long)t * IDIM);
        f16x2 u2  = *(const f16x2*)(u16 + base + (long)t * IDIM);
        int tg = c * TCHUNK + t;
        f16x2 g2 = *(const f16x2*)(proj + (long)tg * (2 * IDIM) + IDIM + i0);
        f16x2 res;
        #pragma unroll
        for (int ch = 0; ch < 2; ++ch) {
            float dt = (float)dt2[ch];
            float uv = (float)u2[ch];
            float dtu = dt * uv;
            float y = 0.f;
            #pragma unroll
            for (int n = 0; n < 16; ++n) {
                float dA = __expf(dt * A[ch][n]);
                s[ch][n] = s[ch][n] * dA + dtu * Bs[t * 16 + n];
                y += s[ch][n] * Cs[t * 16 + n];
            }
            float g = (float)g2[ch];
            float Dch = ch ? Dv.y : Dv.x;
            res[ch] = (_Float16)((y + uv * Dch) * silu_f(g));
        }
        *(f16x2*)(y16 + base + (long)t * IDIM) = res;
    }
}

// ---------------------------------------------------------------------------
extern "C" void kernel_launch(void* const* d_in, const int* in_sizes, int n_in,
                              void* d_out, int out_size, void* d_ws, size_t ws_size,
                              hipStream_t stream) {
    const float* x_in  = (const float*)d_in[0];
    const float* w_in  = (const float*)d_in[1];
    const float* cw    = (const float*)d_in[2];
    const float* cb    = (const float*)d_in[3];
    const float* xw    = (const float*)d_in[4];
    const float* dtw   = (const float*)d_in[5];
    const float* dtb   = (const float*)d_in[6];
    const float* alog  = (const float*)d_in[7];
    const float* Dp    = (const float*)d_in[8];
    const float* ow    = (const float*)d_in[9];
    float* out = (float*)d_out;

    char* p = (char*)d_ws;
    auto alloc = [&](size_t bytes) { char* r = p; p += (bytes + 255) & ~255ull; return r; };
    _Float16* Xf    = (_Float16*)alloc((size_t)LSEQ * HID * 2);
    _Float16* Wt1   = (_Float16*)alloc((size_t)2 * IDIM * HID * 2);      // (2I,H); dead after in_proj
    _Float16* proj  = (_Float16*)alloc((size_t)LSEQ * 2 * IDIM * 2);
    _Float16* u16   = (_Float16*)alloc((size_t)LSEQ * IDIM * 2);
    _Float16* Wt2   = (_Float16*)alloc((size_t)256 * IDIM * 2);          // (GDIM pad 256, I)
    float*    ssm   = (float*)alloc((size_t)LSEQ * GDIM * 4);
    _Float16* dtin  = (_Float16*)alloc((size_t)LSEQ * RRANK * 2);
    _Float16* Wt3   = (_Float16*)alloc((size_t)IDIM * RRANK * 2);        // (I,R)
    _Float16* dtf   = (_Float16*)alloc((size_t)LSEQ * IDIM * 2);
    _Float16* Wt4   = (_Float16*)alloc((size_t)HID * IDIM * 2);          // (H,I)
    _Float16* y16   = (_Float16*)alloc((size_t)LSEQ * IDIM * 2);

    // aliases into dead Wt1 region (33.5 MB), lifetime-ordered:
    //   xpart f32 x16 (xproj) -> Pc/Sc f16 (scan) -> opart f16 (out_proj)
    float* xpart = (float*)Wt1;                        // 16 x 2048 x 256 f32 = 33.5 MB (exact)
    _Float16* Pc = (_Float16*)Wt1;                     // G*I*16 f16 = 8.4 MB
    _Float16* Sc = Pc + (size_t)GCHUNK * IDIM * 16;    // 8.4 MB
    _Float16* opart = (_Float16*)Wt1;                  // 2 x L*H f16 = 16.8 MB

    // 1. prep: Wt1 transpose + X convert
    prep_kernel<<<5120, 256, 0, stream>>>(x_in, w_in, Xf, Wt1);
    // 2. in_proj GEMM + independent Wt2/3/4 transposes (overlapped, no barrier)
    inproj_plus_kernel<<<1024 + 192 + 128 + 2048, 256, 0, stream>>>(
        Xf, Wt1, proj, xw, dtw, ow, Wt2, Wt3, Wt4);
    // 3. conv + SiLU -> u16
    conv_silu_kernel<<<(LSEQ / 4) * (IDIM / 8) / 256, 256, 0, stream>>>(proj, cw, cb, u16);
    // 4. x_proj split-K x16: (L,I)@(I,256pad) -> partials
    gemm_bt_kernel<float, false><<<dim3(2, LSEQ / BM, 16), 256, 0, stream>>>(
        u16, Wt2, xpart, LSEQ, 256, IDIM, IDIM / 16, nullptr);
    xproj_reduce_kernel<<<(LSEQ * GDIM + 255) / 256, 256, 0, stream>>>(xpart, ssm, dtin);
    // 5. dt_proj (+bias+softplus): (L,R)@(R,I) -> dtf f16
    gemm_bt_kernel<_Float16, true><<<dim3(IDIM / 128, LSEQ / BM, 1), 256, 0, stream>>>(
        dtin, Wt3, dtf, LSEQ, IDIM, RRANK, RRANK, dtb);
    // 6. chunked scan
    scan_pass1_kernel<<<dim3(IDIM / 512, GCHUNK), 256, 0, stream>>>(
        dtf, ssm, u16, alog, Pc, Sc);
    scan_combine_kernel<<<(IDIM * NSTATE / 2) / 256, 256, 0, stream>>>(Pc, Sc);
    scan_pass3_kernel<<<dim3(IDIM / 512, GCHUNK), 256, 0, stream>>>(
        dtf, ssm, u16, proj, alog, Dp, Sc, y16);
    // 7. out_proj split-K x2 (f16 partials) -> reduce to f32 out
    gemm_bt_kernel<_Float16, false><<<dim3(HID / 128, LSEQ / BM, 2), 256, 0, stream>>>(
        y16, Wt4, opart, LSEQ, HID, IDIM, IDIM / 2, nullptr);
    opart_reduce_kernel<<<(LSEQ * HID / 32) / 256, 256, 0, stream>>>(opart, out);
}